// Round 8
// baseline (39.670 us; speedup 1.0000x reference)
//
#include <hip/hip_runtime.h>

// PS-RoI-Align (torchvision ps_roi_align semantics).
// feat: [4, 784, 112, 112] fp32; rois: [K,5]; out: [K, 16, 7, 7] fp32.
//
// R7: depth-2 plane pipeline, triple buffer, one barrier per round.
//   R5/R6 post-mortem: per-round time identical (2.7us) -> limiter is the
//   BURSTY per-CU HBM demand (56KB issued at round start, then silence until
//   next round). Depth-2 keeps ~2 stages (100KB) queued per CU continuously,
//   so round time approaches fair-share service 50KB/(6.3TB/s/256) ~ 2.0us.
//   Schedule per round i:
//     wait vmcnt(cw)   // own loads of plane P(i) done; P(i+1) may stay in flight
//     s_barrier        // all waves' chunks of buf[i%3] landed
//     compute P(i) from buf[i%3]
//     stage P(i+2) -> buf[(i+2)%3]   // issued AFTER compute: single barrier
//                                    // suffices (all waves passed barrier i =>
//                                    // done reading buf[(i+2)%3] in round i-1)
//   49 real 1KB chunks, wave0 owns 7, waves 1-7 own 6 (no dummy re-reads);
//   per-wave literal vmcnt via wave-uniform branch. 256 blocks, contiguous
//   12-13 plane ranges (13-round critical path).

#define PP 7
#define SR 2
#define SCALEF 0.0625f

constexpr int Cc     = 784;            // Cout * P * P
constexpr int Hh     = 112;
constexpr int Ww     = 112;
constexpr int PLANE  = Hh * Ww;        // 12544 floats = 50176 B
constexpr int CHUNKS = 49;             // 1KB chunks (64 lanes x 16 B)
constexpr int NBLK   = 256;            // 1 block / CU
constexpr int TPB    = 512;            // 8 waves
constexpr int RPT    = 2;              // rois per thread (K <= 1024)

__global__ __launch_bounds__(TPB) void psroi_persist_kernel(
    const float* __restrict__ feat,
    const float* __restrict__ rois,
    float* __restrict__ out,
    int K, int nplanes)
{
    __shared__ float buf[3][PLANE];    // 150528 B <= 160 KB

    int tid  = threadIdx.x;
    int wave = tid >> 6;
    int lane = tid & 63;

    // ---- parse roi params once per block into registers ----
    int   rb[RPT];
    float x1[RPT], y1[RPT], bsh[RPT], bsw[RPT];
#pragma unroll
    for (int j = 0; j < RPT; ++j) {
        int k = tid + j * TPB;
        if (k < K) {
            const float* r = rois + (size_t)k * 5;
            rb[j]  = (int)r[0];
            x1[j]  = r[1] * SCALEF - 0.5f;
            y1[j]  = r[2] * SCALEF - 0.5f;
            float rw = fmaxf(r[3] * SCALEF - 0.5f - x1[j], 0.1f);
            float rh = fmaxf(r[4] * SCALEF - 0.5f - y1[j], 0.1f);
            bsh[j] = rh * (1.0f / (float)PP);
            bsw[j] = rw * (1.0f / (float)PP);
        } else {
            rb[j] = -1;
        }
    }

    // ---- async stage one plane into buf[bi]; wave w owns chunks w, w+8, ... ----
    auto stage = [&](int bi, int p) {
        const float* src = feat + (size_t)p * PLANE;
        for (int j = wave; j < CHUNKS; j += TPB / 64) {
            __builtin_amdgcn_global_load_lds(
                (const __attribute__((address_space(1))) void*)(src + j * 256 + lane * 4),
                (__attribute__((address_space(3))) void*)(&buf[bi][j * 256]),
                16, 0, 0);
        }
    };

    // balanced contiguous partition: blocks 0..63 get 13 planes, rest 12
    int per   = nplanes / NBLK;
    int rem   = nplanes % NBLK;
    int bid   = blockIdx.x;
    int start = bid * per + min(bid, rem);
    int cnt   = per + (bid < rem ? 1 : 0);

    stage(0, start);                       // pipeline fill: depth 2
    if (cnt > 1) stage(1, start + 1);

    for (int i = 0; i < cnt; ++i) {
        // wait for OWN chunks of plane P(i); allow P(i+1)'s stage in flight
        if (i + 1 < cnt) {
            if (wave == 0) asm volatile("s_waitcnt vmcnt(7)" ::: "memory");
            else           asm volatile("s_waitcnt vmcnt(6)" ::: "memory");
        } else {
            asm volatile("s_waitcnt vmcnt(0)" ::: "memory");
        }
        __builtin_amdgcn_s_barrier();      // all waves' chunks landed

        int p  = start + i;
        int b  = p / Cc;
        int c  = p % Cc;
        int pw = c % PP;
        int ph = (c % (PP * PP)) / PP;
        const float* pl = buf[i % 3];

#pragma unroll
        for (int j = 0; j < RPT; ++j) {
            if (rb[j] != b) continue;
            float acc = 0.0f;
#pragma unroll
            for (int iy = 0; iy < SR; ++iy) {
                float gy = ((float)iy + 0.5f) / (float)SR;
                float y  = y1[j] + ((float)ph + gy) * bsh[j];
                bool  vy = (y >= -1.0f) && (y <= (float)Hh);
                float yc = fminf(fmaxf(y, 0.0f), (float)(Hh - 1));
                int   yl = (int)yc;            // yc >= 0 -> trunc == floor
                int   yh = min(yl + 1, Hh - 1);
                float ly = yc - (float)yl;
                float hy = 1.0f - ly;
#pragma unroll
                for (int ix = 0; ix < SR; ++ix) {
                    float gx = ((float)ix + 0.5f) / (float)SR;
                    float x  = x1[j] + ((float)pw + gx) * bsw[j];
                    bool  vx = (x >= -1.0f) && (x <= (float)Ww);
                    float xc = fminf(fmaxf(x, 0.0f), (float)(Ww - 1));
                    int   xl = (int)xc;
                    int   xh = min(xl + 1, Ww - 1);
                    float lx = xc - (float)xl;
                    float hx = 1.0f - lx;

                    float v = hy * hx * pl[yl * Ww + xl]
                            + hy * lx * pl[yl * Ww + xh]
                            + ly * hx * pl[yh * Ww + xl]
                            + ly * lx * pl[yh * Ww + xh];
                    acc += (vy && vx) ? v : 0.0f;
                }
            }
            int k = tid + j * TPB;
            out[(size_t)k * Cc + c] = acc * (1.0f / (float)(SR * SR));
        }

        // keep two stages in flight: issue P(i+2) after compute
        if (i + 2 < cnt) stage((i + 2) % 3, p + 2);
    }
}

extern "C" void kernel_launch(void* const* d_in, const int* in_sizes, int n_in,
                              void* d_out, int out_size, void* d_ws, size_t ws_size,
                              hipStream_t stream) {
    const float* feat = (const float*)d_in[0];
    const float* rois = (const float*)d_in[1];
    float* out = (float*)d_out;

    int K = in_sizes[1] / 5;
    int nplanes = in_sizes[0] / PLANE;          // N * Cc = 3136
    psroi_persist_kernel<<<NBLK, TPB, 0, stream>>>(feat, rois, out, K, nplanes);
}

// Round 9
// 39.177 us; speedup vs baseline: 1.0126x; 1.0126x over previous
//
#include <hip/hip_runtime.h>

// PS-RoI-Align (torchvision ps_roi_align semantics).
// feat: [4, 784, 112, 112] fp32; rois: [K,5]; out: [K, 16, 7, 7] fp32.
//
// R8: concurrency instead of pipeline depth.
//   R5/R6/R7 post-mortem: per-round time pinned at ~2.7us/50KB/CU for any
//   1-block/CU schedule (depth-1, counted-vmcnt, depth-2 all identical or
//   worse) -> limiter is latency absorption, not schedule. R0 proved the
//   memory system gives 6.07 TB/s to this data with enough independent
//   waves (12.5K waves, random gathers, 360MB/59.3us).
//   => 768 persistent blocks (3 co-resident per CU via 50KB LDS each),
//   4 waves per block, single buffer, stage -> sync -> compute -> sync.
//   Three independent barrier groups per CU interleave stage/compute
//   phases, keeping HBM demand continuous and absorbing tail latency.
//   Roi params parsed once per block (RPT=4).

#define PP 7
#define SR 2
#define SCALEF 0.0625f

constexpr int Cc     = 784;            // Cout * P * P
constexpr int Hh     = 112;
constexpr int Ww     = 112;
constexpr int PLANE  = Hh * Ww;        // 12544 floats = 50176 B
constexpr int CHUNKS = 49;             // 1KB chunks (64 lanes x 16 B)
constexpr int NBLK   = 768;            // 3 per CU
constexpr int TPB    = 256;            // 4 waves
constexpr int RPT    = 4;              // rois per thread (K <= 1024)

__global__ __launch_bounds__(TPB) void psroi_persist_kernel(
    const float* __restrict__ feat,
    const float* __restrict__ rois,
    float* __restrict__ out,
    int K, int nplanes)
{
    __shared__ float buf[PLANE];       // 50176 B -> 3 blocks/CU

    int tid  = threadIdx.x;
    int wave = tid >> 6;
    int lane = tid & 63;

    // ---- parse roi params once per block into registers ----
    int   rb[RPT];
    float x1[RPT], y1[RPT], bsh[RPT], bsw[RPT];
#pragma unroll
    for (int j = 0; j < RPT; ++j) {
        int k = tid + j * TPB;
        if (k < K) {
            const float* r = rois + (size_t)k * 5;
            rb[j]  = (int)r[0];
            x1[j]  = r[1] * SCALEF - 0.5f;
            y1[j]  = r[2] * SCALEF - 0.5f;
            float rw = fmaxf(r[3] * SCALEF - 0.5f - x1[j], 0.1f);
            float rh = fmaxf(r[4] * SCALEF - 0.5f - y1[j], 0.1f);
            bsh[j] = rh * (1.0f / (float)PP);
            bsw[j] = rw * (1.0f / (float)PP);
        } else {
            rb[j] = -1;
        }
    }

    // balanced contiguous partition: per=4 rem=64 at nplanes=3136
    int per   = nplanes / NBLK;
    int rem   = nplanes % NBLK;
    int bid   = blockIdx.x;
    int start = bid * per + min(bid, rem);
    int cnt   = per + (bid < rem ? 1 : 0);

    for (int i = 0; i < cnt; ++i) {
        int p = start + i;

        // ---- async stage plane p into LDS (wave w: chunks w, w+4, ...) ----
        {
            const float* src = feat + (size_t)p * PLANE;
            for (int j = wave; j < CHUNKS; j += TPB / 64) {
                __builtin_amdgcn_global_load_lds(
                    (const __attribute__((address_space(1))) void*)(src + j * 256 + lane * 4),
                    (__attribute__((address_space(3))) void*)(&buf[j * 256]),
                    16, 0, 0);
            }
        }
        __syncthreads();               // vmcnt(0) drain + barrier: plane landed

        int b  = p / Cc;
        int c  = p % Cc;
        int pw = c % PP;
        int ph = (c % (PP * PP)) / PP;

#pragma unroll
        for (int j = 0; j < RPT; ++j) {
            if (rb[j] != b) continue;
            float acc = 0.0f;
#pragma unroll
            for (int iy = 0; iy < SR; ++iy) {
                float gy = ((float)iy + 0.5f) / (float)SR;
                float y  = y1[j] + ((float)ph + gy) * bsh[j];
                bool  vy = (y >= -1.0f) && (y <= (float)Hh);
                float yc = fminf(fmaxf(y, 0.0f), (float)(Hh - 1));
                int   yl = (int)yc;            // yc >= 0 -> trunc == floor
                int   yh = min(yl + 1, Hh - 1);
                float ly = yc - (float)yl;
                float hy = 1.0f - ly;
#pragma unroll
                for (int ix = 0; ix < SR; ++ix) {
                    float gx = ((float)ix + 0.5f) / (float)SR;
                    float x  = x1[j] + ((float)pw + gx) * bsw[j];
                    bool  vx = (x >= -1.0f) && (x <= (float)Ww);
                    float xc = fminf(fmaxf(x, 0.0f), (float)(Ww - 1));
                    int   xl = (int)xc;
                    int   xh = min(xl + 1, Ww - 1);
                    float lx = xc - (float)xl;
                    float hx = 1.0f - lx;

                    float v = hy * hx * buf[yl * Ww + xl]
                            + hy * lx * buf[yl * Ww + xh]
                            + ly * hx * buf[yh * Ww + xl]
                            + ly * lx * buf[yh * Ww + xh];
                    acc += (vy && vx) ? v : 0.0f;
                }
            }
            int k = tid + j * TPB;
            out[(size_t)k * Cc + c] = acc * (1.0f / (float)(SR * SR));
        }

        __syncthreads();               // all waves done reading before next stage
    }
}

extern "C" void kernel_launch(void* const* d_in, const int* in_sizes, int n_in,
                              void* d_out, int out_size, void* d_ws, size_t ws_size,
                              hipStream_t stream) {
    const float* feat = (const float*)d_in[0];
    const float* rois = (const float*)d_in[1];
    float* out = (float*)d_out;

    int K = in_sizes[1] / 5;
    int nplanes = in_sizes[0] / PLANE;          // N * Cc = 3136
    psroi_persist_kernel<<<NBLK, TPB, 0, stream>>>(feat, rois, out, K, nplanes);
}